// Round 2
// baseline (336.892 us; speedup 1.0000x reference)
//
#include <hip/hip_runtime.h>
#include <hip/hip_bf16.h>
#include <cstdint>

// ---------------------------------------------------------------------------
// DynamicRouting: hat = enc @ W^T  (fp16 MFMA, fp32 accum), then 3 routing
// iterations fused in one kernel (hat_c staged in 128 KB LDS per capsule).
// enc: [C=512, K=64, H=1024] fp32;  W: [1024,1024] fp32;  out c: [512,1024] fp32
// ---------------------------------------------------------------------------

#define C_DIM 512
#define KCAPS 64
#define H_DIM 1024
#define M_DIM (C_DIM * KCAPS)   // 32768

typedef _Float16 h8 __attribute__((ext_vector_type(8)));
typedef _Float16 h4 __attribute__((ext_vector_type(4)));
typedef float f4 __attribute__((ext_vector_type(4)));

// ---------------- convert fp32 -> fp16 (vectorized) ----------------
__global__ void cvt_f32_f16(const float* __restrict__ in, _Float16* __restrict__ out, int n4) {
    int i = blockIdx.x * blockDim.x + threadIdx.x;
    int stride = gridDim.x * blockDim.x;
    for (; i < n4; i += stride) {
        float4 v = ((const float4*)in)[i];
        h4 o;
        o[0] = (_Float16)v.x; o[1] = (_Float16)v.y;
        o[2] = (_Float16)v.z; o[3] = (_Float16)v.w;
        ((h4*)out)[i] = o;
    }
}

// ---------------- GEMM: hat[m,o] = sum_h A[m,h] * B[o,h] ----------------
// m97-style 128x128 tile, BK=64, 4 waves, global_load_lds width 16.
// + T1 XCD-aware block swizzle (nwg=2048 divisible by 8).
__device__ __forceinline__ void gload16(const _Float16* g, _Float16* l) {
    __builtin_amdgcn_global_load_lds(
        (const __attribute__((address_space(1))) void*)g,
        (__attribute__((address_space(3))) void*)l, 16, 0, 0);
}

__global__ __launch_bounds__(256) void gemm_f16_bt(const _Float16* __restrict__ A,
                                                   const _Float16* __restrict__ B,
                                                   _Float16* __restrict__ Cmat) {
    __shared__ _Float16 As[128 * 64] __attribute__((aligned(16)));
    __shared__ _Float16 Bs[128 * 64] __attribute__((aligned(16)));
    const int tid  = threadIdx.x;
    const int lane = tid & 63;
    const int wid  = tid >> 6;           // 4 waves
    // T1: XCD-aware swizzle. bid%8 == XCD; give each XCD a contiguous tm range
    // so the 8 blocks sharing an A-panel run on the same XCD's L2.
    const int bid  = blockIdx.x;
    const int swz  = (bid & 7) * 256 + (bid >> 3);   // bijective, 2048 % 8 == 0
    const int tm   = swz >> 3;           // 256 row tiles
    const int tn   = swz & 7;            // 8 col tiles
    const int wr   = wid >> 1, wc = wid & 1;

    f4 acc[4][4] = {};

    const int r8 = lane >> 3;            // row within 8-row chunk
    const int c8 = (lane & 7) * 8;       // half-index col within 64

    const _Float16* Abase = A + (size_t)(tm * 128) * H_DIM;
    const _Float16* Bbase = B + (size_t)(tn * 128) * H_DIM;

    for (int kt = 0; kt < H_DIM; kt += 64) {
        // stage A,B tiles: each wave issues 4+4 global_load_lds (1 KB each)
        #pragma unroll
        for (int i = 0; i < 4; ++i) {
            const int chunk = wid * 4 + i;       // 0..15, 8 rows each
            const int row   = chunk * 8 + r8;
            gload16(Abase + (size_t)row * H_DIM + kt + c8, &As[chunk * 512]);
            gload16(Bbase + (size_t)row * H_DIM + kt + c8, &Bs[chunk * 512]);
        }
        __syncthreads();   // compiler emits vmcnt(0) drain before barrier

        #pragma unroll
        for (int kk = 0; kk < 64; kk += 32) {
            h8 af[4], bf[4];
            const int kidx = kk + ((lane >> 4) << 3);
            #pragma unroll
            for (int m = 0; m < 4; ++m)
                af[m] = *(const h8*)&As[(wr * 64 + m * 16 + (lane & 15)) * 64 + kidx];
            #pragma unroll
            for (int n = 0; n < 4; ++n)
                bf[n] = *(const h8*)&Bs[(wc * 64 + n * 16 + (lane & 15)) * 64 + kidx];
            #pragma unroll
            for (int m = 0; m < 4; ++m)
                #pragma unroll
                for (int n = 0; n < 4; ++n)
                    acc[m][n] = __builtin_amdgcn_mfma_f32_16x16x32_f16(af[m], bf[n], acc[m][n], 0, 0, 0);
        }
        __syncthreads();
    }

    // epilogue: C/D layout col=lane&15, row=(lane>>4)*4+q (m89-verified family)
    const int crow0 = tm * 128 + wr * 64;
    const int ccol0 = tn * 128 + wc * 64;
    #pragma unroll
    for (int m = 0; m < 4; ++m) {
        #pragma unroll
        for (int n = 0; n < 4; ++n) {
            const int col = ccol0 + n * 16 + (lane & 15);
            #pragma unroll
            for (int q = 0; q < 4; ++q) {
                const int row = crow0 + m * 16 + (lane >> 4) * 4 + q;
                Cmat[(size_t)row * H_DIM + col] = (_Float16)acc[m][n][q];
            }
        }
    }
}

// ---------------- fused routing v2: hat_c staged in LDS ----------------
__device__ __forceinline__ float2 upk(unsigned int u) {
    unsigned short ul = (unsigned short)(u & 0xffffu);
    unsigned short uh = (unsigned short)(u >> 16);
    _Float16 lo, hi;
    __builtin_memcpy(&lo, &ul, 2);
    __builtin_memcpy(&hi, &uh, 2);
    return make_float2((float)lo, (float)hi);
}

__global__ __launch_bounds__(512) void routing2(const _Float16* __restrict__ hat,
                                                float* __restrict__ out) {
    __shared__ _Float16 hat_s[KCAPS * H_DIM] __attribute__((aligned(16))); // 128 KB
    __shared__ float b_lds[KCAPS];
    __shared__ float d_lds[KCAPS];
    __shared__ float c_lds[H_DIM];    // 4 KB
    __shared__ float red[8];
    __shared__ float norm_sh;

    const int c    = blockIdx.x;      // capsule 0..511
    const int t    = threadIdx.x;     // owns h = 2t, 2t+1
    const int lane = t & 63;
    const int wid  = t >> 6;          // 8 waves

    // stage hat_c (64 x 1024 fp16, row-major, linear): 128 chunks of 1 KB
    const _Float16* gbase = hat + (size_t)c * (KCAPS * H_DIM);
    #pragma unroll
    for (int i = 0; i < 16; ++i) {
        const int chunk = wid * 16 + i;                      // wave-uniform
        gload16(gbase + chunk * 512 + lane * 8, &hat_s[chunk * 512]);
    }
    if (t < 64) b_lds[t] = 0.0f;
    __syncthreads();

    float cx = 0.0f, cy = 0.0f;

    for (int it = 0; it < 3; ++it) {
        // softmax over K=64 (wave 0)
        if (wid == 0) {
            float bv = b_lds[lane];
            float mx = bv;
            #pragma unroll
            for (int s = 1; s < 64; s <<= 1) mx = fmaxf(mx, __shfl_xor(mx, s, 64));
            float e = __expf(bv - mx);
            float sum = e;
            #pragma unroll
            for (int s = 1; s < 64; s <<= 1) sum += __shfl_xor(sum, s, 64);
            d_lds[lane] = e / sum;
        }
        __syncthreads();

        // c_hat[h] = sum_k hat[k,h] d[k] — thread t owns h = 2t, 2t+1
        float chx = 0.0f, chy = 0.0f;
        #pragma unroll
        for (int k = 0; k < 64; ++k) {
            unsigned int u = *(const unsigned int*)&hat_s[k * H_DIM + 2 * t];
            float2 f = upk(u);
            float dk = d_lds[k];
            chx = fmaf(f.x, dk, chx);
            chy = fmaf(f.y, dk, chy);
        }

        // ||c_hat||^2: wave reduce + cross-wave
        float nn = chx * chx + chy * chy;
        #pragma unroll
        for (int s = 1; s < 64; s <<= 1) nn += __shfl_xor(nn, s, 64);
        if (lane == 0) red[wid] = nn;
        __syncthreads();
        if (t == 0) {
            float tot = 0.0f;
            #pragma unroll
            for (int w = 0; w < 8; ++w) tot += red[w];
            norm_sh = tot;
        }
        __syncthreads();
        const float ns = norm_sh;
        const float scale = (ns / (1.0f + ns)) / sqrtf(ns + 1e-9f);
        cx = chx * scale;
        cy = chy * scale;

        if (it == 2) break;

        c_lds[2 * t]     = cx;
        c_lds[2 * t + 1] = cy;
        __syncthreads();

        // b[k] += sum_h hat[k,h] c[h] — wave w handles k = w*8 .. w*8+7,
        // lane owns h = lane*16 .. lane*16+15
        float4 cc[4];
        #pragma unroll
        for (int q = 0; q < 4; ++q)
            cc[q] = *(const float4*)&c_lds[lane * 16 + q * 4];

        #pragma unroll
        for (int j = 0; j < 8; ++j) {
            const int k = wid * 8 + j;
            const h8* hp = (const h8*)&hat_s[k * H_DIM + lane * 16];
            float p = 0.0f;
            #pragma unroll
            for (int half = 0; half < 2; ++half) {
                h8 v = hp[half];
                const float* cf = (const float*)&cc[half * 2];
                #pragma unroll
                for (int e = 0; e < 8; ++e)
                    p = fmaf((float)v[e], cf[e], p);
            }
            #pragma unroll
            for (int s = 1; s < 64; s <<= 1) p += __shfl_xor(p, s, 64);
            if (lane == 0) b_lds[k] += p;
        }
        __syncthreads();
    }

    float2 o;
    o.x = cx; o.y = cy;
    *(float2*)&out[(size_t)c * H_DIM + 2 * t] = o;
}

// ---------------------------------------------------------------------------
extern "C" void kernel_launch(void* const* d_in, const int* in_sizes, int n_in,
                              void* d_out, int out_size, void* d_ws, size_t ws_size,
                              hipStream_t stream) {
    const float* enc = (const float*)d_in[0];   // [512,64,1024] fp32
    const float* Wf  = (const float*)d_in[1];   // [1024,1024] fp32
    float* out = (float*)d_out;                 // [512,1024] fp32

    char* ws = (char*)d_ws;
    _Float16* enc16 = (_Float16*)ws;                                   // 64 MB
    _Float16* W16   = (_Float16*)(ws + (size_t)67108864);              //  2 MB
    _Float16* hat16 = (_Float16*)(ws + (size_t)67108864 + 2097152);    // 64 MB

    const int n_enc = C_DIM * KCAPS * H_DIM;   // 33554432
    const int n_w   = H_DIM * H_DIM;           // 1048576

    cvt_f32_f16<<<2048, 256, 0, stream>>>(enc, enc16, n_enc / 4);
    cvt_f32_f16<<<512, 256, 0, stream>>>(Wf, W16, n_w / 4);

    gemm_f16_bt<<<(M_DIM / 128) * (H_DIM / 128), 256, 0, stream>>>(enc16, W16, hat16);

    routing2<<<C_DIM, 512, 0, stream>>>(hat16, out);
}

// Round 3
// 331.110 us; speedup vs baseline: 1.0175x; 1.0175x over previous
//
#include <hip/hip_runtime.h>
#include <hip/hip_bf16.h>
#include <cstdint>

// ---------------------------------------------------------------------------
// DynamicRouting fused: one block per capsule c computes
//   hat_c[64,1024] = enc_c[64,1024] @ W^T   (fp16 MFMA, fp32 accum)
// into 128 KB LDS, then runs all 3 routing iterations in place.
// W (2 MB fp16) is L2-resident; B-fragments are read straight from global.
// enc: [512,64,1024] fp32; W: [1024,1024] fp32; out: [512,1024] fp32
// ---------------------------------------------------------------------------

#define C_DIM 512
#define KCAPS 64
#define H_DIM 1024

typedef _Float16 h8 __attribute__((ext_vector_type(8)));
typedef _Float16 h4 __attribute__((ext_vector_type(4)));
typedef float f4 __attribute__((ext_vector_type(4)));

// ---------------- convert fp32 -> fp16 (W only, 2 MB) ----------------
__global__ void cvt_f32_f16(const float* __restrict__ in, _Float16* __restrict__ out, int n4) {
    int i = blockIdx.x * blockDim.x + threadIdx.x;
    int stride = gridDim.x * blockDim.x;
    for (; i < n4; i += stride) {
        float4 v = ((const float4*)in)[i];
        h4 o;
        o[0] = (_Float16)v.x; o[1] = (_Float16)v.y;
        o[2] = (_Float16)v.z; o[3] = (_Float16)v.w;
        ((h4*)out)[i] = o;
    }
}

__device__ __forceinline__ float2 upk(unsigned int u) {
    unsigned short ul = (unsigned short)(u & 0xffffu);
    unsigned short uh = (unsigned short)(u >> 16);
    _Float16 lo, hi;
    __builtin_memcpy(&lo, &ul, 2);
    __builtin_memcpy(&hi, &uh, 2);
    return make_float2((float)lo, (float)hi);
}

// ---------------- fused GEMM + routing ----------------
__global__ __launch_bounds__(512, 2) void fused_caps(const float* __restrict__ enc,
                                                     const _Float16* __restrict__ W16,
                                                     float* __restrict__ out) {
    // LDS: hat 128 KB + A-tile 8 KB + routing scratch ~4.6 KB = ~140.6 KB
    __shared__ _Float16 hat_s[KCAPS * H_DIM] __attribute__((aligned(16)));   // [64][1024]
    __shared__ _Float16 As[8 * 64 * 8] __attribute__((aligned(16)));         // [kgr][row][8]
    __shared__ float c_lds[H_DIM];
    __shared__ float b_lds[KCAPS];
    __shared__ float d_lds[KCAPS];
    __shared__ float red[8];
    __shared__ float norm_sh;

    const int c    = blockIdx.x;      // capsule 0..511
    const int t    = threadIdx.x;     // 512 threads = 8 waves
    const int lane = t & 63;
    const int wid  = t >> 6;

    // ---------------- GEMM phase ----------------
    // wave wid owns output cols [wid*128, wid*128+128)
    const float*     Aenc = enc + (size_t)c * (KCAPS * H_DIM);
    const _Float16*  Wb   = W16 + (size_t)(wid * 128) * H_DIM;

    // A staging map: thread t loads row=t>>3, k-chunk (t&7)*8 .. +8 (8 fp32 = 32B)
    const int arow = t >> 3;
    const int akgr = t & 7;
    const float* aptr = Aenc + arow * H_DIM + akgr * 8;

    if (t < KCAPS) b_lds[t] = 0.0f;

    f4 acc[4][8] = {};

    float4 pre0 = *(const float4*)(aptr);
    float4 pre1 = *(const float4*)(aptr + 4);

    for (int kt = 0; kt < H_DIM; kt += 64) {
        __syncthreads();   // previous compute done reading As
        {
            h8 av;
            av[0] = (_Float16)pre0.x; av[1] = (_Float16)pre0.y;
            av[2] = (_Float16)pre0.z; av[3] = (_Float16)pre0.w;
            av[4] = (_Float16)pre1.x; av[5] = (_Float16)pre1.y;
            av[6] = (_Float16)pre1.z; av[7] = (_Float16)pre1.w;
            *(h8*)&As[akgr * 512 + arow * 8] = av;   // ds_write_b128
        }
        if (kt + 64 < H_DIM) {
            pre0 = *(const float4*)(aptr + kt + 64);      // prefetch next tile
            pre1 = *(const float4*)(aptr + kt + 64 + 4);  // (reg loads: no barrier drain)
        }
        __syncthreads();   // As ready

        #pragma unroll
        for (int s = 0; s < 2; ++s) {
            const int kq = (lane >> 4);            // quarter-wave k-group
            h8 bf[8];
            #pragma unroll
            for (int n = 0; n < 8; ++n)
                bf[n] = *(const h8*)(Wb + (size_t)(n * 16 + (lane & 15)) * H_DIM
                                     + kt + s * 32 + kq * 8);
            h8 af[4];
            #pragma unroll
            for (int m = 0; m < 4; ++m)
                af[m] = *(const h8*)&As[(s * 4 + kq) * 512 + (m * 16 + (lane & 15)) * 8];
            #pragma unroll
            for (int m = 0; m < 4; ++m)
                #pragma unroll
                for (int n = 0; n < 8; ++n)
                    acc[m][n] = __builtin_amdgcn_mfma_f32_16x16x32_f16(af[m], bf[n], acc[m][n], 0, 0, 0);
        }
    }

    __syncthreads();
    // epilogue: acc -> hat_s[row][col], row = m*16+(lane>>4)*4+q, col = wid*128+n*16+(lane&15)
    #pragma unroll
    for (int m = 0; m < 4; ++m) {
        #pragma unroll
        for (int n = 0; n < 8; ++n) {
            const int col = wid * 128 + n * 16 + (lane & 15);
            #pragma unroll
            for (int q = 0; q < 4; ++q) {
                const int row = m * 16 + (lane >> 4) * 4 + q;
                hat_s[row * H_DIM + col] = (_Float16)acc[m][n][q];
            }
        }
    }
    __syncthreads();

    // ---------------- routing phase (3 iterations) ----------------
    float cx = 0.0f, cy = 0.0f;

    for (int it = 0; it < 3; ++it) {
        // softmax over K=64 (wave 0); b=0 on iter 0 -> uniform 1/64
        if (wid == 0) {
            float bv = b_lds[lane];
            float mx = bv;
            #pragma unroll
            for (int s = 1; s < 64; s <<= 1) mx = fmaxf(mx, __shfl_xor(mx, s, 64));
            float e = __expf(bv - mx);
            float sum = e;
            #pragma unroll
            for (int s = 1; s < 64; s <<= 1) sum += __shfl_xor(sum, s, 64);
            d_lds[lane] = e / sum;
        }
        __syncthreads();

        // c_hat[h] = sum_k hat[k,h] d[k] — thread t owns h = 2t, 2t+1
        // bank = t mod 32 per k-step: 2-way (free)
        float chx = 0.0f, chy = 0.0f;
        #pragma unroll
        for (int k = 0; k < 64; ++k) {
            unsigned int u = *(const unsigned int*)&hat_s[k * H_DIM + 2 * t];
            float2 f = upk(u);
            float dk = d_lds[k];
            chx = fmaf(f.x, dk, chx);
            chy = fmaf(f.y, dk, chy);
        }

        // ||c_hat||^2
        float nn = chx * chx + chy * chy;
        #pragma unroll
        for (int s = 1; s < 64; s <<= 1) nn += __shfl_xor(nn, s, 64);
        if (lane == 0) red[wid] = nn;
        __syncthreads();
        if (t == 0) {
            float tot = 0.0f;
            #pragma unroll
            for (int w = 0; w < 8; ++w) tot += red[w];
            norm_sh = tot;
        }
        __syncthreads();
        const float ns = norm_sh;
        const float scale = (ns / (1.0f + ns)) / sqrtf(ns + 1e-9f);
        cx = chx * scale;
        cy = chy * scale;

        if (it == 2) break;

        c_lds[2 * t]     = cx;
        c_lds[2 * t + 1] = cy;
        __syncthreads();

        // b[k] += sum_h hat[k,h] c[h] — wave w: k = w*8..w*8+7;
        // lane reads h-pairs at (lane + 64*i)*2 -> bank = lane mod 32 (conflict-free)
        #pragma unroll
        for (int j = 0; j < 8; ++j) {
            const int k = wid * 8 + j;
            float p = 0.0f;
            #pragma unroll
            for (int i = 0; i < 8; ++i) {
                const int hp = lane + 64 * i;     // h-pair index 0..511
                unsigned int u = *(const unsigned int*)&hat_s[k * H_DIM + 2 * hp];
                float2 f = upk(u);
                float2 cc = *(const float2*)&c_lds[2 * hp];
                p = fmaf(f.x, cc.x, p);
                p = fmaf(f.y, cc.y, p);
            }
            #pragma unroll
            for (int s = 1; s < 64; s <<= 1) p += __shfl_xor(p, s, 64);
            if (lane == 0) b_lds[k] += p;
        }
        __syncthreads();
    }

    float2 o;
    o.x = cx; o.y = cy;
    *(float2*)&out[(size_t)c * H_DIM + 2 * t] = o;
}

// ---------------------------------------------------------------------------
extern "C" void kernel_launch(void* const* d_in, const int* in_sizes, int n_in,
                              void* d_out, int out_size, void* d_ws, size_t ws_size,
                              hipStream_t stream) {
    const float* enc = (const float*)d_in[0];   // [512,64,1024] fp32
    const float* Wf  = (const float*)d_in[1];   // [1024,1024] fp32
    float* out = (float*)d_out;                 // [512,1024] fp32

    _Float16* W16 = (_Float16*)d_ws;            // 2 MB

    const int n_w = H_DIM * H_DIM;              // 1048576

    cvt_f32_f16<<<512, 256, 0, stream>>>(Wf, W16, n_w / 4);
    fused_caps<<<C_DIM, 512, 0, stream>>>(enc, W16, out);
}